// Round 1
// baseline (506.349 us; speedup 1.0000x reference)
//
#include <hip/hip_runtime.h>

typedef __bf16 bf16x8_t __attribute__((ext_vector_type(8)));
typedef float f32x4_t __attribute__((ext_vector_type(4)));

__device__ __forceinline__ unsigned short f2bf(float f) {
  unsigned u = __float_as_uint(f);
  u = (u + 0x7FFFu + ((u >> 16) & 1u)) >> 16;
  return (unsigned short)u;
}
__device__ __forceinline__ float bf2f(unsigned short h) {
  return __uint_as_float(((unsigned)h) << 16);
}
// swizzled byte offset inside a [rows][32-bf16] LDS tile (64B rows):
// XOR the 16B-quarter index with ((row>>1)&3) -> reads land on 8 distinct
// 4-bank slots per 16-lane group (2-way aliasing = free, per m136).
__device__ __forceinline__ int swz(int row, int b) {
  return row * 64 + (b ^ (((row >> 1) & 3) << 4));
}

// NT GEMM: C[M,N] = alpha * A[M,K] * Bt[N,K]^T + bias[N]
// A: fp32 or bf16 (A_F32), Bt: always bf16. 128x128 tile, 4 waves (2x2),
// each wave 64x64 via 4x4 mfma_f32_16x16x32_bf16 fragments. BK=32.
template<bool A_F32, bool OUT_BF16, bool TRANS_OUT, bool HAS_BIAS>
__global__ __launch_bounds__(256, 2)
void gemm_nt(const void* __restrict__ Ap, const unsigned short* __restrict__ Bt,
             void* __restrict__ Cp, const float* __restrict__ bias,
             int M, int N, int K, int lda, int ldb, int ldc,
             long strideA, long strideB, long strideC, float alpha)
{
  __shared__ __align__(16) char smem[2][2][8192];  // [dbuf][A/B][128x32 bf16]
  const int tid = threadIdx.x;
  const int lane = tid & 63;
  const int wave = tid >> 6;
  const int wr = wave >> 1, wc = wave & 1;
  const int bm = blockIdx.y * 128, bn = blockIdx.x * 128;
  const long zA = (long)blockIdx.z * strideA;
  const long zB = (long)blockIdx.z * strideB;
  const long zC = (long)blockIdx.z * strideC;

  float4 raf[4];  // A staging regs (fp32 path)
  uint4  rab[2];  // A staging regs (bf16 path)
  uint4  rbb[2];  // B staging regs

  auto load_tile = [&](int kt) {
    const int k0 = kt * 32;
    if constexpr (A_F32) {
      const float* A = (const float*)Ap + zA;
#pragma unroll
      for (int it = 0; it < 4; ++it) {
        const int id = it * 256 + tid;                     // 0..1023
        raf[it] = *(const float4*)(A + (long)(bm + (id >> 3)) * lda + (k0 + (id & 7) * 4));
      }
    } else {
      const unsigned short* A = (const unsigned short*)Ap + zA;
#pragma unroll
      for (int it = 0; it < 2; ++it) {
        const int id = it * 256 + tid;                     // 0..511
        rab[it] = *(const uint4*)(A + (long)(bm + (id >> 2)) * lda + (k0 + (id & 3) * 8));
      }
    }
    const unsigned short* Bp = Bt + zB;
#pragma unroll
    for (int it = 0; it < 2; ++it) {
      const int id = it * 256 + tid;
      rbb[it] = *(const uint4*)(Bp + (long)(bn + (id >> 2)) * ldb + (k0 + (id & 3) * 8));
    }
  };

  auto write_tile = [&](int buf) {
    char* sa = smem[buf][0];
    char* sb = smem[buf][1];
    if constexpr (A_F32) {
#pragma unroll
      for (int it = 0; it < 4; ++it) {
        const int id = it * 256 + tid;
        const int row = id >> 3, kc = (id & 7) * 4;
        const float4 v = raf[it];
        unsigned long long w =
              (unsigned long long)f2bf(v.x)
            | ((unsigned long long)f2bf(v.y) << 16)
            | ((unsigned long long)f2bf(v.z) << 32)
            | ((unsigned long long)f2bf(v.w) << 48);
        *(unsigned long long*)(sa + swz(row, kc * 2)) = w;
      }
    } else {
#pragma unroll
      for (int it = 0; it < 2; ++it) {
        const int id = it * 256 + tid;
        *(uint4*)(sa + swz(id >> 2, (id & 3) * 16)) = rab[it];
      }
    }
#pragma unroll
    for (int it = 0; it < 2; ++it) {
      const int id = it * 256 + tid;
      *(uint4*)(sb + swz(id >> 2, (id & 3) * 16)) = rbb[it];
    }
  };

  f32x4_t acc[4][4];
  const f32x4_t z4 = {0.f, 0.f, 0.f, 0.f};
#pragma unroll
  for (int m = 0; m < 4; ++m)
#pragma unroll
    for (int n = 0; n < 4; ++n) acc[m][n] = z4;

  load_tile(0);
  write_tile(0);
  __syncthreads();

  const int nt = K >> 5;
  const int rA = wr * 64 + (lane & 15);
  const int rB = wc * 64 + (lane & 15);
  const int kq = (lane >> 4) * 16;  // byte offset of this lane's 8 bf16 along K

  for (int kt = 0; kt < nt; ++kt) {
    const int cur = kt & 1;
    const bool more = (kt + 1 < nt);
    if (more) load_tile(kt + 1);   // issue global loads early (hide under MFMA)
    const char* sa = smem[cur][0];
    const char* sb = smem[cur][1];
    bf16x8_t af[4], bfv[4];
#pragma unroll
    for (int m = 0; m < 4; ++m)
      af[m] = __builtin_bit_cast(bf16x8_t, *(const uint4*)(sa + swz(rA + m * 16, kq)));
#pragma unroll
    for (int n = 0; n < 4; ++n)
      bfv[n] = __builtin_bit_cast(bf16x8_t, *(const uint4*)(sb + swz(rB + n * 16, kq)));
#pragma unroll
    for (int m = 0; m < 4; ++m)
#pragma unroll
      for (int n = 0; n < 4; ++n)
        acc[m][n] = __builtin_amdgcn_mfma_f32_16x16x32_bf16(af[m], bfv[n], acc[m][n], 0, 0, 0);
    if (more) write_tile(cur ^ 1); // write-late: vmcnt wait lands after MFMAs
    __syncthreads();
  }

  // Epilogue. C/D layout: col = lane&15, row = (lane>>4)*4 + i   [m89/m91]
  const int r0 = (lane >> 4) * 4;
  const int c0 = lane & 15;
#pragma unroll
  for (int m = 0; m < 4; ++m) {
    const int grow0 = bm + wr * 64 + m * 16 + r0;
#pragma unroll
    for (int n = 0; n < 4; ++n) {
      const int gcol = bn + wc * 64 + n * 16 + c0;
      float bv_ = 0.f;
      if constexpr (HAS_BIAS) bv_ = bias[gcol];
#pragma unroll
      for (int i = 0; i < 4; ++i) {
        const float v = acc[m][n][i] * alpha + bv_;
        if constexpr (TRANS_OUT) {
          ((unsigned short*)Cp)[zC + (long)gcol * ldc + (grow0 + i)] = f2bf(v);
        } else if constexpr (OUT_BF16) {
          ((unsigned short*)Cp)[zC + (long)(grow0 + i) * ldc + gcol] = f2bf(v);
        } else {
          ((float*)Cp)[zC + (long)(grow0 + i) * ldc + gcol] = v;
        }
      }
    }
  }
}

// Wt[n][k] = (bf16) W[k][n], D=1024
__global__ __launch_bounds__(256)
void wtrans(const float* __restrict__ W, unsigned short* __restrict__ Wt) {
  __shared__ float tile[32][33];
  const int bx = blockIdx.x * 32;  // n
  const int by = blockIdx.y * 32;  // k
  const int t = threadIdx.x;
  const int c = t & 31, r0 = t >> 5;
#pragma unroll
  for (int i = 0; i < 4; ++i)
    tile[r0 + i * 8][c] = W[(long)(by + r0 + i * 8) * 1024 + bx + c];
  __syncthreads();
#pragma unroll
  for (int i = 0; i < 4; ++i)
    Wt[(long)(bx + r0 + i * 8) * 1024 + by + c] = f2bf(tile[c][r0 + i * 8]);
}

// In-place softmax over rows of S (bf16), 2048 cols, one block per row.
__global__ __launch_bounds__(256)
void softmax_rows(unsigned short* __restrict__ S) {
  const long row = blockIdx.x;
  unsigned short* p = S + row * 2048;
  const int t = threadIdx.x;
  uint4 v = ((uint4*)p)[t];                // 8 bf16 per thread
  unsigned short* hp = (unsigned short*)&v;
  float f[8];
#pragma unroll
  for (int j = 0; j < 8; ++j) f[j] = bf2f(hp[j]);

  float m = f[0];
#pragma unroll
  for (int j = 1; j < 8; ++j) m = fmaxf(m, f[j]);
#pragma unroll
  for (int s = 32; s; s >>= 1) m = fmaxf(m, __shfl_xor(m, s, 64));
  __shared__ float redm[4];
  __shared__ float reds[4];
  const int wave = t >> 6, lane = t & 63;
  if (lane == 0) redm[wave] = m;
  __syncthreads();
  m = fmaxf(fmaxf(redm[0], redm[1]), fmaxf(redm[2], redm[3]));

  float sum = 0.f;
#pragma unroll
  for (int j = 0; j < 8; ++j) { f[j] = __expf(f[j] - m); sum += f[j]; }
#pragma unroll
  for (int s = 32; s; s >>= 1) sum += __shfl_xor(sum, s, 64);
  if (lane == 0) reds[wave] = sum;
  __syncthreads();
  sum = reds[0] + reds[1] + reds[2] + reds[3];
  const float inv = 1.0f / sum;
#pragma unroll
  for (int j = 0; j < 8; ++j) hp[j] = f2bf(f[j] * inv);
  ((uint4*)p)[t] = v;
}

extern "C" void kernel_launch(void* const* d_in, const int* in_sizes, int n_in,
                              void* d_out, int out_size, void* d_ws, size_t ws_size,
                              hipStream_t stream) {
  const float* x  = (const float*)d_in[0];
  const float* y  = (const float*)d_in[1];
  const float* Wq = (const float*)d_in[2];
  const float* bq = (const float*)d_in[3];
  const float* Wk = (const float*)d_in[4];
  const float* bk = (const float*)d_in[5];
  const float* Wv = (const float*)d_in[6];
  const float* bv = (const float*)d_in[7];
  float* out = (float*)d_out;

  const int B = 4, Sx = 2048, Sy = 2048, D = 1024;
  unsigned short* ws  = (unsigned short*)d_ws;
  unsigned short* Wqt = ws;                                  // [D][D] bf16 (W^T)
  unsigned short* Wkt = Wqt + (size_t)D * D;
  unsigned short* Wvt = Wkt + (size_t)D * D;
  unsigned short* Qb  = Wvt + (size_t)D * D;                 // [B*Sx][D] bf16
  unsigned short* Kb  = Qb + (size_t)B * Sx * D;             // [B*Sy][D] bf16
  unsigned short* Vt  = Kb + (size_t)B * Sy * D;             // [B][D][Sy] bf16
  unsigned short* Sb  = Vt + (size_t)B * Sy * D;             // [B][Sx][Sy] bf16

  dim3 blk(256);

  wtrans<<<dim3(32, 32), blk, 0, stream>>>(Wq, Wqt);
  wtrans<<<dim3(32, 32), blk, 0, stream>>>(Wk, Wkt);
  wtrans<<<dim3(32, 32), blk, 0, stream>>>(Wv, Wvt);

  // Q = x @ Wq + bq  -> bf16 [8192,1024]
  gemm_nt<true, true, false, true><<<dim3(8, 64, 1), blk, 0, stream>>>(
      x, Wqt, Qb, bq, B * Sx, D, D, D, D, D, 0, 0, 0, 1.0f);
  // K = y @ Wk + bk  -> bf16 [8192,1024]
  gemm_nt<true, true, false, true><<<dim3(8, 64, 1), blk, 0, stream>>>(
      y, Wkt, Kb, bk, B * Sy, D, D, D, D, D, 0, 0, 0, 1.0f);
  // V^T: per batch out[b][d][t] = (y_b @ Wv + bv)[t][d]  -> bf16 [B][D][Sy]
  gemm_nt<true, true, true, true><<<dim3(8, 16, 4), blk, 0, stream>>>(
      y, Wvt, Vt, bv, Sy, D, D, D, D, Sy,
      (long)Sy * D, 0, (long)D * Sy, 1.0f);

  // S = (Q_b @ K_b^T) / sqrt(D)  -> bf16 [B][Sx][Sy]
  gemm_nt<false, true, false, false><<<dim3(16, 16, 4), blk, 0, stream>>>(
      Qb, Kb, Sb, nullptr, Sx, Sy, D, D, D, Sy,
      (long)Sx * D, (long)Sy * D, (long)Sx * Sy, 0.03125f);

  softmax_rows<<<dim3(B * Sx), blk, 0, stream>>>(Sb);

  // out = P_b @ V_b : NT against Vt [D][Sy] -> fp32 [B][Sx][D]
  gemm_nt<false, false, false, false><<<dim3(8, 16, 4), blk, 0, stream>>>(
      Sb, Vt, out, nullptr, Sx, D, Sy, Sy, Sy, D,
      (long)Sx * Sy, (long)D * Sy, (long)Sx * D, 1.0f);
}

// Round 2
// 208.321 us; speedup vs baseline: 2.4306x; 2.4306x over previous
//
#include <hip/hip_runtime.h>

typedef __bf16 bf16x8_t __attribute__((ext_vector_type(8)));
typedef float f32x4_t __attribute__((ext_vector_type(4)));
typedef unsigned short ushort_t;

__device__ __forceinline__ unsigned short f2bf(float f) {
  unsigned u = __float_as_uint(f);
  u = (u + 0x7FFFu + ((u >> 16) & 1u)) >> 16;
  return (unsigned short)u;
}
__device__ __forceinline__ float bf2f(unsigned short h) {
  return __uint_as_float(((unsigned)h) << 16);
}

// async global->LDS, 16B per lane. LDS dest = wave-uniform base + lane*16.
__device__ __forceinline__ void gload16(const void* g, void* l) {
  __builtin_amdgcn_global_load_lds(
      (const __attribute__((address_space(1))) unsigned int*)g,
      (__attribute__((address_space(3))) unsigned int*)l, 16, 0, 0);
}

// ---------------------------------------------------------------------------
// NT GEMM, all-bf16 inputs: C[M,N] = alpha * A[M,K] * Bt[N,K]^T (+ bias[N])
// 128x128 tile, BK=32, 4 waves (2x2), 4x4 mfma_f32_16x16x32_bf16 per wave.
// Staging via global_load_lds (linear LDS dest); bank-conflict fix via
// pre-swizzled GLOBAL source + swizzled ds_read (both-sides rule, m104/m173):
//   LDS(row, chunk) holds global(row, chunk ^ ((row>>1)&3)), chunk = 16B unit.
// ---------------------------------------------------------------------------
template<bool OUT_BF16, bool HAS_BIAS>
__global__ __launch_bounds__(256, 3)
void gemm_nt(const ushort_t* __restrict__ A, const ushort_t* __restrict__ Bt,
             void* __restrict__ Cp, const float* __restrict__ bias,
             int gx, int gy, int K, int lda, int ldb, int ldc,
             long sA, long sB, long sC, float alpha)
{
  __shared__ __align__(16) ushort_t smem[2][8192];  // per buf: A[0..4095] B[4096..8191]
  const int tid = threadIdx.x;
  const int lane = tid & 63;
  const int wave = tid >> 6;

  // bijective XCD-chunked block swizzle (nwg % 8 == 0 for all launches here)
  const int per = gridDim.x >> 3;
  int wg = blockIdx.x;
  wg = (wg & 7) * per + (wg >> 3);
  const int bz = wg / (gx * gy);
  const int rr = wg - bz * gx * gy;
  const int by = rr / gx, bx = rr - by * gx;
  const int bm = by * 128, bn = bx * 128;

  const ushort_t* Ab = A + (long)bz * sA;
  const ushort_t* Bb = Bt + (long)bz * sB;

  // staging: 8 x 1KB instrs per operand-tile; wave w issues q=w and q=w+4.
  // instr q covers rows q*16 + (lane>>2), 16B-chunk (lane&3), source-swizzled.
  const int r_s0 = wave * 16 + (lane >> 2);
  const int r_s1 = (wave + 4) * 16 + (lane >> 2);
  const int c_s0 = (((lane & 3) ^ ((r_s0 >> 1) & 3)) << 3);  // elems
  const int c_s1 = (((lane & 3) ^ ((r_s1 >> 1) & 3)) << 3);
  const ushort_t* gA0 = Ab + (long)(bm + r_s0) * lda + c_s0;
  const ushort_t* gA1 = Ab + (long)(bm + r_s1) * lda + c_s1;
  const ushort_t* gB0 = Bb + (long)(bn + r_s0) * ldb + c_s0;
  const ushort_t* gB1 = Bb + (long)(bn + r_s1) * ldb + c_s1;

  auto stage = [&](int kt, int buf) {
    const int k0 = kt << 5;
    ushort_t* s = smem[buf];
    gload16(gA0 + k0, s + wave * 512);
    gload16(gA1 + k0, s + (wave + 4) * 512);
    gload16(gB0 + k0, s + 4096 + wave * 512);
    gload16(gB1 + k0, s + 4096 + (wave + 4) * 512);
  };

  // fragment ds_read offsets (ushort units), swizzled to undo the source perm
  const int wr = wave >> 1, wc = wave & 1;
  int offA[4], offB[4];
#pragma unroll
  for (int m = 0; m < 4; ++m) {
    const int row = wr * 64 + m * 16 + (lane & 15);
    offA[m] = row * 32 + ((((lane >> 4) ^ ((row >> 1) & 3))) << 3);
  }
#pragma unroll
  for (int n = 0; n < 4; ++n) {
    const int row = wc * 64 + n * 16 + (lane & 15);
    offB[n] = 4096 + row * 32 + ((((lane >> 4) ^ ((row >> 1) & 3))) << 3);
  }

  f32x4_t acc[4][4];
  const f32x4_t z4 = {0.f, 0.f, 0.f, 0.f};
#pragma unroll
  for (int m = 0; m < 4; ++m)
#pragma unroll
    for (int n = 0; n < 4; ++n) acc[m][n] = z4;

  stage(0, 0);
  __syncthreads();

  const int nt = K >> 5;
  for (int kt = 0; kt < nt; ++kt) {
    const int cur = kt & 1;
    if (kt + 1 < nt) stage(kt + 1, cur ^ 1);  // in flight across the MFMAs
    const ushort_t* s = smem[cur];
    bf16x8_t af[4], bfv[4];
#pragma unroll
    for (int m = 0; m < 4; ++m)
      af[m] = __builtin_bit_cast(bf16x8_t, *(const uint4*)(s + offA[m]));
#pragma unroll
    for (int n = 0; n < 4; ++n)
      bfv[n] = __builtin_bit_cast(bf16x8_t, *(const uint4*)(s + offB[n]));
#pragma unroll
    for (int m = 0; m < 4; ++m)
#pragma unroll
      for (int n = 0; n < 4; ++n)
        acc[m][n] = __builtin_amdgcn_mfma_f32_16x16x32_bf16(af[m], bfv[n], acc[m][n], 0, 0, 0);
    __syncthreads();
  }

  // Epilogue. C/D layout: col = lane&15, row = (lane>>4)*4 + i   [m89/m91]
  const long zC = (long)bz * sC;
  const int r0 = (lane >> 4) * 4;
  const int c0 = lane & 15;
#pragma unroll
  for (int m = 0; m < 4; ++m) {
    const int grow0 = bm + wr * 64 + m * 16 + r0;
#pragma unroll
    for (int n = 0; n < 4; ++n) {
      const int gcol = bn + wc * 64 + n * 16 + c0;
      float bv_ = 0.f;
      if constexpr (HAS_BIAS) bv_ = bias[gcol];
#pragma unroll
      for (int i = 0; i < 4; ++i) {
        const float v = acc[m][n][i] * alpha + bv_;
        if constexpr (OUT_BF16) {
          ((ushort_t*)Cp)[zC + (long)(grow0 + i) * ldc + gcol] = f2bf(v);
        } else {
          ((float*)Cp)[zC + (long)(grow0 + i) * ldc + gcol] = v;
        }
      }
    }
  }
}

// fp32 -> bf16 bulk convert, 8 elems/thread, exact grid
__global__ __launch_bounds__(256)
void conv_f32_bf16(const float* __restrict__ in, ushort_t* __restrict__ out) {
  const long i = (long)blockIdx.x * 256 + threadIdx.x;
  const float4 a = ((const float4*)in)[i * 2];
  const float4 b = ((const float4*)in)[i * 2 + 1];
  uint4 o;
  o.x = (unsigned)f2bf(a.x) | ((unsigned)f2bf(a.y) << 16);
  o.y = (unsigned)f2bf(a.z) | ((unsigned)f2bf(a.w) << 16);
  o.z = (unsigned)f2bf(b.x) | ((unsigned)f2bf(b.y) << 16);
  o.w = (unsigned)f2bf(b.z) | ((unsigned)f2bf(b.w) << 16);
  ((uint4*)out)[i] = o;
}

// Wt[n][k] = (bf16) W[k][n], D=1024
__global__ __launch_bounds__(256)
void wtrans(const float* __restrict__ W, ushort_t* __restrict__ Wt) {
  __shared__ float tile[32][33];
  const int bx = blockIdx.x * 32;  // n
  const int by = blockIdx.y * 32;  // k
  const int t = threadIdx.x;
  const int c = t & 31, r0 = t >> 5;
#pragma unroll
  for (int i = 0; i < 4; ++i)
    tile[r0 + i * 8][c] = W[(long)(by + r0 + i * 8) * 1024 + bx + c];
  __syncthreads();
#pragma unroll
  for (int i = 0; i < 4; ++i)
    Wt[(long)(bx + r0 + i * 8) * 1024 + by + c] = f2bf(tile[c][r0 + i * 8]);
}

// bf16 transpose: in [rows][cols] -> out [cols][rows], 64x64 tiles
__global__ __launch_bounds__(256)
void transpose_bf16(const ushort_t* __restrict__ in, ushort_t* __restrict__ out,
                    int rows, int cols) {
  __shared__ ushort_t t[64][65];
  in += (long)blockIdx.z * rows * cols;
  out += (long)blockIdx.z * rows * cols;
  const int r0 = blockIdx.y * 64, c0 = blockIdx.x * 64;
  const int tc = threadIdx.x & 31;   // col-pair
  const int tr = threadIdx.x >> 5;   // 0..7
#pragma unroll
  for (int i = 0; i < 8; ++i) {
    const unsigned v = *(const unsigned*)(in + (long)(r0 + tr + 8 * i) * cols + c0 + tc * 2);
    t[tr + 8 * i][tc * 2] = (ushort_t)(v & 0xffff);
    t[tr + 8 * i][tc * 2 + 1] = (ushort_t)(v >> 16);
  }
  __syncthreads();
#pragma unroll
  for (int i = 0; i < 8; ++i) {
    const unsigned v = (unsigned)t[tc * 2][tr + 8 * i] |
                       ((unsigned)t[tc * 2 + 1][tr + 8 * i] << 16);
    *(unsigned*)(out + (long)(c0 + tr + 8 * i) * rows + r0 + tc * 2) = v;
  }
}

// In-place softmax over rows of S (bf16), 2048 cols, one block per row.
__global__ __launch_bounds__(256)
void softmax_rows(ushort_t* __restrict__ S) {
  const long row = blockIdx.x;
  ushort_t* p = S + row * 2048;
  const int t = threadIdx.x;
  uint4 v = ((uint4*)p)[t];  // 8 bf16 per thread
  ushort_t* hp = (ushort_t*)&v;
  float f[8];
#pragma unroll
  for (int j = 0; j < 8; ++j) f[j] = bf2f(hp[j]);

  float m = f[0];
#pragma unroll
  for (int j = 1; j < 8; ++j) m = fmaxf(m, f[j]);
#pragma unroll
  for (int s = 32; s; s >>= 1) m = fmaxf(m, __shfl_xor(m, s, 64));
  __shared__ float redm[4];
  __shared__ float reds[4];
  const int wave = t >> 6, lane = t & 63;
  if (lane == 0) redm[wave] = m;
  __syncthreads();
  m = fmaxf(fmaxf(redm[0], redm[1]), fmaxf(redm[2], redm[3]));

  float sum = 0.f;
#pragma unroll
  for (int j = 0; j < 8; ++j) { f[j] = __expf(f[j] - m); sum += f[j]; }
#pragma unroll
  for (int s = 32; s; s >>= 1) sum += __shfl_xor(sum, s, 64);
  if (lane == 0) reds[wave] = sum;
  __syncthreads();
  sum = reds[0] + reds[1] + reds[2] + reds[3];
  const float inv = 1.0f / sum;
#pragma unroll
  for (int j = 0; j < 8; ++j) hp[j] = f2bf(f[j] * inv);
  ((uint4*)p)[t] = v;
}

extern "C" void kernel_launch(void* const* d_in, const int* in_sizes, int n_in,
                              void* d_out, int out_size, void* d_ws, size_t ws_size,
                              hipStream_t stream) {
  const float* x  = (const float*)d_in[0];
  const float* y  = (const float*)d_in[1];
  const float* Wq = (const float*)d_in[2];
  const float* bq = (const float*)d_in[3];
  const float* Wk = (const float*)d_in[4];
  const float* bk = (const float*)d_in[5];
  const float* Wv = (const float*)d_in[6];
  const float* bv = (const float*)d_in[7];
  float* out = (float*)d_out;

  const int B = 4, Sx = 2048, Sy = 2048, D = 1024;
  const long M = (long)B * Sx;  // 8192

  // workspace layout (ushort elems), with aliasing:
  //   Vn aliases Sb (consumed by transpose before S-gemm writes Sb)
  //   Vt aliases xb (xb free after Q-gemm)
  ushort_t* ws  = (ushort_t*)d_ws;
  ushort_t* Wqt = ws;                         // 1M
  ushort_t* Wkt = Wqt + (1u << 20);
  ushort_t* Wvt = Wkt + (1u << 20);
  ushort_t* Qb  = Wvt + (1u << 20);           // 8M  [B*Sx][D]
  ushort_t* Kb  = Qb + (8u << 20);            // 8M  [B*Sy][D]
  ushort_t* Sb  = Kb + (8u << 20);            // 16M [B][Sx][Sy]
  ushort_t* xb  = Sb + (16u << 20);           // 8M  [B*Sx][D]
  ushort_t* yb  = xb + (8u << 20);            // 8M  [B*Sy][D]
  ushort_t* Vn  = Sb;                         // alias
  ushort_t* Vt  = xb;                         // alias [B][D][Sy]

  dim3 blk(256);

  conv_f32_bf16<<<dim3(4096), blk, 0, stream>>>(x, xb);
  conv_f32_bf16<<<dim3(4096), blk, 0, stream>>>(y, yb);
  wtrans<<<dim3(32, 32), blk, 0, stream>>>(Wq, Wqt);
  wtrans<<<dim3(32, 32), blk, 0, stream>>>(Wk, Wkt);
  wtrans<<<dim3(32, 32), blk, 0, stream>>>(Wv, Wvt);

  // Q = xb @ Wqt^T + bq -> bf16 [8192,1024]   grid 8x64 = 512
  gemm_nt<true, true><<<dim3(512), blk, 0, stream>>>(
      xb, Wqt, Qb, bq, 8, 64, D, D, D, D, 0, 0, 0, 1.0f);
  // K = yb @ Wkt^T + bk
  gemm_nt<true, true><<<dim3(512), blk, 0, stream>>>(
      yb, Wkt, Kb, bk, 8, 64, D, D, D, D, 0, 0, 0, 1.0f);
  // V (normal layout) -> Vn [8192,1024]
  gemm_nt<true, true><<<dim3(512), blk, 0, stream>>>(
      yb, Wvt, Vn, bv, 8, 64, D, D, D, D, 0, 0, 0, 1.0f);
  // Vt[b][d][t] = Vn[b][t][d]
  transpose_bf16<<<dim3(16, 32, 4), blk, 0, stream>>>(Vn, Vt, Sy, D);

  // S = (Q_b @ K_b^T) / 32 -> bf16 [B][Sx][Sy]   grid 16x16x4 = 1024
  gemm_nt<true, false><<<dim3(1024), blk, 0, stream>>>(
      Qb, Kb, Sb, nullptr, 16, 16, D, D, D, Sy,
      (long)Sx * D, (long)Sy * D, (long)Sx * Sy, 0.03125f);

  softmax_rows<<<dim3(B * Sx), blk, 0, stream>>>(Sb);

  // out = P_b @ V_b  (NT vs Vt [D][Sy]) -> fp32 [B][Sx][D]  grid 8x16x4 = 512
  gemm_nt<false, false><<<dim3(512), blk, 0, stream>>>(
      Sb, Vt, out, nullptr, 8, 16, Sy, Sy, Sy, D,
      (long)Sx * Sy, (long)D * Sy, (long)Sx * D, 1.0f);
}

// Round 3
// 203.463 us; speedup vs baseline: 2.4887x; 1.0239x over previous
//
#include <hip/hip_runtime.h>

typedef __bf16 bf16x8_t __attribute__((ext_vector_type(8)));
typedef float f32x4_t __attribute__((ext_vector_type(4)));
typedef unsigned short ushort_t;

__device__ __forceinline__ unsigned short f2bf(float f) {
  unsigned u = __float_as_uint(f);
  u = (u + 0x7FFFu + ((u >> 16) & 1u)) >> 16;
  return (unsigned short)u;
}
__device__ __forceinline__ float bf2f(unsigned short h) {
  return __uint_as_float(((unsigned)h) << 16);
}

// async global->LDS, 16B/lane. LDS dest = wave-uniform base + lane*16.
__device__ __forceinline__ void gload16(const void* g, void* l) {
  __builtin_amdgcn_global_load_lds(
      (const __attribute__((address_space(1))) unsigned int*)g,
      (__attribute__((address_space(3))) unsigned int*)l, 16, 0, 0);
}

#define BARRIER() __builtin_amdgcn_s_barrier()
#define LGKM0()                                        \
  do {                                                 \
    asm volatile("s_waitcnt lgkmcnt(0)" ::: "memory"); \
    __builtin_amdgcn_sched_barrier(0);                 \
  } while (0)

// ===========================================================================
// 256x256 8-phase NT GEMM (m201/m218 schedule, plain HIP).
// C[M,N] = alpha*A[M,K]*Bt[N,K]^T (+bias). BK=64, 8 waves (2Mx4N), 512 thr.
// LDS 128KiB: 2 buf x (A 32KB + B 32KB). Halves: A-lo rows0-127 etc.
// Swizzle: LDS(row,chunk16B) holds global(row, chunk^(row&7)); ds_read XORs
// the same (both-sides rule). vmcnt(6) only at tile boundaries.
// ===========================================================================
template<bool OUT_BF16, bool HAS_BIAS>
__global__ __launch_bounds__(512, 2)
void gemm256(const ushort_t* __restrict__ A, const ushort_t* __restrict__ Bt,
             void* __restrict__ Cp, const float* __restrict__ bias,
             int gx, int gy, int K, int lda, int ldb, int ldc,
             long sA, long sB, long sC, float alpha)
{
  __shared__ __align__(16) ushort_t sm[2 * 32768];
  const int tid = threadIdx.x;
  const int lane = tid & 63;
  const int w = tid >> 6;          // wave 0..7
  const int wr = w >> 2, wc = w & 3;

  // bijective XCD-chunked swizzle (all grids here are %8==0)
  const int per = gridDim.x >> 3;
  int wg = blockIdx.x;
  wg = (wg & 7) * per + (wg >> 3);
  const int bz = wg / (gx * gy);
  const int rr = wg - bz * gx * gy;
  const int by = rr / gx, bx = rr - by * gx;
  const int bm = by * 256, bn = bx * 256;

  // ---- staging constants: wave w covers segs {2w,2w+1} = rows w*16..w*16+15
  const int srr = lane >> 3;                   // row within 8-row seg
  const int csw = ((lane & 7) ^ srr) << 3;     // source-swizzled chunk (elems)
  const ushort_t* pA = A + (long)bz * sA + (long)(bm + w * 16 + srr) * lda + csw;
  const ushort_t* pB = Bt + (long)bz * sB + (long)(bn + w * 16 + srr) * ldb + csw;

  auto stA = [&](int buf, int h, int t) {      // stage A half h of K-tile t
    const ushort_t* g = pA + (long)(h * 128) * lda + t * 64;
    ushort_t* d = sm + buf * 32768 + h * 8192 + w * 1024;
    gload16(g, d);
    gload16(g + 8 * lda, d + 512);
  };
  auto stB = [&](int buf, int h, int t) {
    const ushort_t* g = pB + (long)(h * 128) * ldb + t * 64;
    ushort_t* d = sm + buf * 32768 + 16384 + h * 8192 + w * 1024;
    gload16(g, d);
    gload16(g + 8 * ldb, d + 512);
  };

  // ---- fragment read constants (ushort units within buf)
  const int q = lane >> 4, x7 = lane & 7;
  const int cx0 = ((0 + q) ^ x7) << 3;         // ks=0 chunk offset
  const int cx1 = ((4 + q) ^ x7) << 3;         // ks=1
  const int abase = wr * 8192 + (lane & 15) * 64;
  const int bbase = 16384 + wc * 4096 + (lane & 15) * 64;

  f32x4_t acc[8][4];
  const f32x4_t z4 = {0.f, 0.f, 0.f, 0.f};
#pragma unroll
  for (int m = 0; m < 8; ++m)
#pragma unroll
    for (int n = 0; n < 4; ++n) acc[m][n] = z4;

  bf16x8_t a[8], blo[4], bhi[4];

  // ---- prologue: tile0 (4 halves) + tile1 {B-lo,B-hi,A-lo}; wait tile0.
  stA(0, 0, 0); stA(0, 1, 0); stB(0, 0, 0); stB(0, 1, 0);
  stB(1, 0, 1); stB(1, 1, 1); stA(1, 0, 1);
  asm volatile("s_waitcnt vmcnt(6)" ::: "memory");
  __builtin_amdgcn_sched_barrier(0);
  BARRIER();

#define LDX(off) __builtin_bit_cast(bf16x8_t, *(const uint4*)(s + (off)))

  const int nt = K >> 6;
  for (int t = 0; t < nt; ++t) {
    const int buf = t & 1;
    const ushort_t* s = sm + buf * 32768;

    // ---------------- P0: A-frags 0-3 + B-lo; MFMA [0-3][0-1] ----------------
#pragma unroll
    for (int mf = 0; mf < 4; ++mf) {
      a[mf * 2]     = LDX(abase + mf * 1024 + cx0);
      a[mf * 2 + 1] = LDX(abase + mf * 1024 + cx1);
    }
#pragma unroll
    for (int nf = 0; nf < 2; ++nf) {
      blo[nf * 2]     = LDX(bbase + nf * 1024 + cx0);
      blo[nf * 2 + 1] = LDX(bbase + nf * 1024 + cx1);
    }
    if (t + 1 < nt) stA(buf ^ 1, 1, t + 1);    // A-hi(t+1): lastread prev p2
    BARRIER();
    LGKM0();
    __builtin_amdgcn_s_setprio(1);
#pragma unroll
    for (int mf = 0; mf < 4; ++mf)
#pragma unroll
      for (int nf = 0; nf < 2; ++nf) {
        acc[mf][nf] = __builtin_amdgcn_mfma_f32_16x16x32_bf16(a[mf * 2], blo[nf * 2], acc[mf][nf], 0, 0, 0);
        acc[mf][nf] = __builtin_amdgcn_mfma_f32_16x16x32_bf16(a[mf * 2 + 1], blo[nf * 2 + 1], acc[mf][nf], 0, 0, 0);
      }
    __builtin_amdgcn_s_setprio(0);
    BARRIER();

    // ---------------- P1: B-hi; MFMA [0-3][2-3] ----------------
#pragma unroll
    for (int nf = 0; nf < 2; ++nf) {
      bhi[nf * 2]     = LDX(bbase + (nf + 2) * 1024 + cx0);
      bhi[nf * 2 + 1] = LDX(bbase + (nf + 2) * 1024 + cx1);
    }
    if (t + 2 < nt) stB(buf, 0, t + 2);        // B-lo(t+2): lastread p0
    BARRIER();
    LGKM0();
    __builtin_amdgcn_s_setprio(1);
#pragma unroll
    for (int mf = 0; mf < 4; ++mf)
#pragma unroll
      for (int nf = 0; nf < 2; ++nf) {
        acc[mf][nf + 2] = __builtin_amdgcn_mfma_f32_16x16x32_bf16(a[mf * 2], bhi[nf * 2], acc[mf][nf + 2], 0, 0, 0);
        acc[mf][nf + 2] = __builtin_amdgcn_mfma_f32_16x16x32_bf16(a[mf * 2 + 1], bhi[nf * 2 + 1], acc[mf][nf + 2], 0, 0, 0);
      }
    __builtin_amdgcn_s_setprio(0);
    BARRIER();

    // ---------------- P2: A-frags 4-7; MFMA [4-7][2-3] ----------------
#pragma unroll
    for (int mf = 0; mf < 4; ++mf) {
      a[mf * 2]     = LDX(abase + (mf + 4) * 1024 + cx0);
      a[mf * 2 + 1] = LDX(abase + (mf + 4) * 1024 + cx1);
    }
    if (t + 2 < nt) stB(buf, 1, t + 2);        // B-hi(t+2): lastread p1
    BARRIER();
    LGKM0();
    __builtin_amdgcn_s_setprio(1);
#pragma unroll
    for (int mf = 0; mf < 4; ++mf)
#pragma unroll
      for (int nf = 0; nf < 2; ++nf) {
        acc[mf + 4][nf + 2] = __builtin_amdgcn_mfma_f32_16x16x32_bf16(a[mf * 2], bhi[nf * 2], acc[mf + 4][nf + 2], 0, 0, 0);
        acc[mf + 4][nf + 2] = __builtin_amdgcn_mfma_f32_16x16x32_bf16(a[mf * 2 + 1], bhi[nf * 2 + 1], acc[mf + 4][nf + 2], 0, 0, 0);
      }
    __builtin_amdgcn_s_setprio(0);
    BARRIER();

    // ---------------- P3: no reads; MFMA [4-7][0-1]; boundary vmcnt ---------
    if (t + 2 < nt) stA(buf, 0, t + 2);        // A-lo(t+2): lastread p2
    __builtin_amdgcn_s_setprio(1);
#pragma unroll
    for (int mf = 0; mf < 4; ++mf)
#pragma unroll
      for (int nf = 0; nf < 2; ++nf) {
        acc[mf + 4][nf] = __builtin_amdgcn_mfma_f32_16x16x32_bf16(a[mf * 2], blo[nf * 2], acc[mf + 4][nf], 0, 0, 0);
        acc[mf + 4][nf] = __builtin_amdgcn_mfma_f32_16x16x32_bf16(a[mf * 2 + 1], blo[nf * 2 + 1], acc[mf + 4][nf], 0, 0, 0);
      }
    __builtin_amdgcn_s_setprio(0);
    if (t + 1 < nt) {                          // tile t+1 must be resident
      if (t + 2 < nt) asm volatile("s_waitcnt vmcnt(6)" ::: "memory");
      else            asm volatile("s_waitcnt vmcnt(0)" ::: "memory");
      __builtin_amdgcn_sched_barrier(0);
    }
    BARRIER();
  }
#undef LDX

  // ---- epilogue. C/D layout: col=lane&15, row=(lane>>4)*4+i  [m89/m91]
  const long zC = (long)bz * sC;
  const int r0 = q * 4;
  const int c0 = lane & 15;
#pragma unroll
  for (int mf = 0; mf < 8; ++mf) {
    const int grow0 = bm + wr * 128 + mf * 16 + r0;
#pragma unroll
    for (int nf = 0; nf < 4; ++nf) {
      const int gcol = bn + wc * 64 + nf * 16 + c0;
      float bv_ = 0.f;
      if constexpr (HAS_BIAS) bv_ = bias[gcol];
#pragma unroll
      for (int i = 0; i < 4; ++i) {
        const float v = acc[mf][nf][i] * alpha + bv_;
        if constexpr (OUT_BF16) {
          ((ushort_t*)Cp)[zC + (long)(grow0 + i) * ldc + gcol] = f2bf(v);
        } else {
          ((float*)Cp)[zC + (long)(grow0 + i) * ldc + gcol] = v;
        }
      }
    }
  }
}

// ===========================================================================
// 128x128 m97-structure NT GEMM (proven round 2) — kept for PV (grid fill).
// ===========================================================================
template<bool OUT_BF16, bool HAS_BIAS>
__global__ __launch_bounds__(256, 3)
void gemm_nt(const ushort_t* __restrict__ A, const ushort_t* __restrict__ Bt,
             void* __restrict__ Cp, const float* __restrict__ bias,
             int gx, int gy, int K, int lda, int ldb, int ldc,
             long sA, long sB, long sC, float alpha)
{
  __shared__ __align__(16) ushort_t smem[2][8192];
  const int tid = threadIdx.x;
  const int lane = tid & 63;
  const int wave = tid >> 6;

  const int per = gridDim.x >> 3;
  int wg = blockIdx.x;
  wg = (wg & 7) * per + (wg >> 3);
  const int bz = wg / (gx * gy);
  const int rr = wg - bz * gx * gy;
  const int by = rr / gx, bx = rr - by * gx;
  const int bm = by * 128, bn = bx * 128;

  const ushort_t* Ab = A + (long)bz * sA;
  const ushort_t* Bb = Bt + (long)bz * sB;

  const int r_s0 = wave * 16 + (lane >> 2);
  const int r_s1 = (wave + 4) * 16 + (lane >> 2);
  const int c_s0 = (((lane & 3) ^ ((r_s0 >> 1) & 3)) << 3);
  const int c_s1 = (((lane & 3) ^ ((r_s1 >> 1) & 3)) << 3);
  const ushort_t* gA0 = Ab + (long)(bm + r_s0) * lda + c_s0;
  const ushort_t* gA1 = Ab + (long)(bm + r_s1) * lda + c_s1;
  const ushort_t* gB0 = Bb + (long)(bn + r_s0) * ldb + c_s0;
  const ushort_t* gB1 = Bb + (long)(bn + r_s1) * ldb + c_s1;

  auto stage = [&](int kt, int buf) {
    const int k0 = kt << 5;
    ushort_t* s = smem[buf];
    gload16(gA0 + k0, s + wave * 512);
    gload16(gA1 + k0, s + (wave + 4) * 512);
    gload16(gB0 + k0, s + 4096 + wave * 512);
    gload16(gB1 + k0, s + 4096 + (wave + 4) * 512);
  };

  const int wr = wave >> 1, wc = wave & 1;
  int offA[4], offB[4];
#pragma unroll
  for (int m = 0; m < 4; ++m) {
    const int row = wr * 64 + m * 16 + (lane & 15);
    offA[m] = row * 32 + ((((lane >> 4) ^ ((row >> 1) & 3))) << 3);
  }
#pragma unroll
  for (int n = 0; n < 4; ++n) {
    const int row = wc * 64 + n * 16 + (lane & 15);
    offB[n] = 4096 + row * 32 + ((((lane >> 4) ^ ((row >> 1) & 3))) << 3);
  }

  f32x4_t acc[4][4];
  const f32x4_t z4 = {0.f, 0.f, 0.f, 0.f};
#pragma unroll
  for (int m = 0; m < 4; ++m)
#pragma unroll
    for (int n = 0; n < 4; ++n) acc[m][n] = z4;

  stage(0, 0);
  __syncthreads();

  const int nt = K >> 5;
  for (int kt = 0; kt < nt; ++kt) {
    const int cur = kt & 1;
    if (kt + 1 < nt) stage(kt + 1, cur ^ 1);
    const ushort_t* s = smem[cur];
    bf16x8_t af[4], bfv[4];
#pragma unroll
    for (int m = 0; m < 4; ++m)
      af[m] = __builtin_bit_cast(bf16x8_t, *(const uint4*)(s + offA[m]));
#pragma unroll
    for (int n = 0; n < 4; ++n)
      bfv[n] = __builtin_bit_cast(bf16x8_t, *(const uint4*)(s + offB[n]));
#pragma unroll
    for (int m = 0; m < 4; ++m)
#pragma unroll
      for (int n = 0; n < 4; ++n)
        acc[m][n] = __builtin_amdgcn_mfma_f32_16x16x32_bf16(af[m], bfv[n], acc[m][n], 0, 0, 0);
    __syncthreads();
  }

  const long zC = (long)bz * sC;
  const int r0 = (lane >> 4) * 4;
  const int c0 = lane & 15;
#pragma unroll
  for (int m = 0; m < 4; ++m) {
    const int grow0 = bm + wr * 64 + m * 16 + r0;
#pragma unroll
    for (int n = 0; n < 4; ++n) {
      const int gcol = bn + wc * 64 + n * 16 + c0;
      float bv_ = 0.f;
      if constexpr (HAS_BIAS) bv_ = bias[gcol];
#pragma unroll
      for (int i = 0; i < 4; ++i) {
        const float v = acc[m][n][i] * alpha + bv_;
        if constexpr (OUT_BF16) {
          ((ushort_t*)Cp)[zC + (long)(grow0 + i) * ldc + gcol] = f2bf(v);
        } else {
          ((float*)Cp)[zC + (long)(grow0 + i) * ldc + gcol] = v;
        }
      }
    }
  }
}

// fp32 -> bf16 bulk convert, 8 elems/thread
__global__ __launch_bounds__(256)
void conv_f32_bf16(const float* __restrict__ in, ushort_t* __restrict__ out) {
  const long i = (long)blockIdx.x * 256 + threadIdx.x;
  const float4 a = ((const float4*)in)[i * 2];
  const float4 b = ((const float4*)in)[i * 2 + 1];
  uint4 o;
  o.x = (unsigned)f2bf(a.x) | ((unsigned)f2bf(a.y) << 16);
  o.y = (unsigned)f2bf(a.z) | ((unsigned)f2bf(a.w) << 16);
  o.z = (unsigned)f2bf(b.x) | ((unsigned)f2bf(b.y) << 16);
  o.w = (unsigned)f2bf(b.z) | ((unsigned)f2bf(b.w) << 16);
  ((uint4*)out)[i] = o;
}

// Wt[n][k] = (bf16) W[k][n], D=1024
__global__ __launch_bounds__(256)
void wtrans(const float* __restrict__ W, ushort_t* __restrict__ Wt) {
  __shared__ float tile[32][33];
  const int bx = blockIdx.x * 32;
  const int by = blockIdx.y * 32;
  const int t = threadIdx.x;
  const int c = t & 31, r0 = t >> 5;
#pragma unroll
  for (int i = 0; i < 4; ++i)
    tile[r0 + i * 8][c] = W[(long)(by + r0 + i * 8) * 1024 + bx + c];
  __syncthreads();
#pragma unroll
  for (int i = 0; i < 4; ++i)
    Wt[(long)(bx + r0 + i * 8) * 1024 + by + c] = f2bf(tile[c][r0 + i * 8]);
}

__global__ __launch_bounds__(256)
void bconcat(const float* __restrict__ a, const float* __restrict__ b,
             float* __restrict__ o) {
  const int i = blockIdx.x * 256 + threadIdx.x;
  o[i] = (i < 1024) ? a[i] : b[i - 1024];
}

// bf16 transpose with strides: out[c][r] = in[r][c], 64x64 tiles per batch
__global__ __launch_bounds__(256)
void transpose_bf16(const ushort_t* __restrict__ in, ushort_t* __restrict__ out,
                    int ld_in, int ld_out, long in_bs, long out_bs) {
  __shared__ ushort_t tt[64][65];
  in += (long)blockIdx.z * in_bs;
  out += (long)blockIdx.z * out_bs;
  const int r0 = blockIdx.y * 64, c0 = blockIdx.x * 64;
  const int tc = threadIdx.x & 31;
  const int tr = threadIdx.x >> 5;
#pragma unroll
  for (int i = 0; i < 8; ++i) {
    const unsigned v = *(const unsigned*)(in + (long)(r0 + tr + 8 * i) * ld_in + c0 + tc * 2);
    tt[tr + 8 * i][tc * 2] = (ushort_t)(v & 0xffff);
    tt[tr + 8 * i][tc * 2 + 1] = (ushort_t)(v >> 16);
  }
  __syncthreads();
#pragma unroll
  for (int i = 0; i < 8; ++i) {
    const unsigned v = (unsigned)tt[tc * 2][tr + 8 * i] |
                       ((unsigned)tt[tc * 2 + 1][tr + 8 * i] << 16);
    *(unsigned*)(out + (long)(c0 + tr + 8 * i) * ld_out + r0 + tc * 2) = v;
  }
}

// In-place softmax over rows of S (bf16), 2048 cols, one block per row.
__global__ __launch_bounds__(256)
void softmax_rows(ushort_t* __restrict__ S) {
  const long row = blockIdx.x;
  ushort_t* p = S + row * 2048;
  const int t = threadIdx.x;
  uint4 v = ((uint4*)p)[t];
  ushort_t* hp = (ushort_t*)&v;
  float f[8];
#pragma unroll
  for (int j = 0; j < 8; ++j) f[j] = bf2f(hp[j]);

  float m = f[0];
#pragma unroll
  for (int j = 1; j < 8; ++j) m = fmaxf(m, f[j]);
#pragma unroll
  for (int s = 32; s; s >>= 1) m = fmaxf(m, __shfl_xor(m, s, 64));
  __shared__ float redm[4];
  __shared__ float reds[4];
  const int wave = t >> 6, lane = t & 63;
  if (lane == 0) redm[wave] = m;
  __syncthreads();
  m = fmaxf(fmaxf(redm[0], redm[1]), fmaxf(redm[2], redm[3]));

  float sum = 0.f;
#pragma unroll
  for (int j = 0; j < 8; ++j) { f[j] = __expf(f[j] - m); sum += f[j]; }
#pragma unroll
  for (int s = 32; s; s >>= 1) sum += __shfl_xor(sum, s, 64);
  if (lane == 0) reds[wave] = sum;
  __syncthreads();
  sum = reds[0] + reds[1] + reds[2] + reds[3];
  const float inv = 1.0f / sum;
#pragma unroll
  for (int j = 0; j < 8; ++j) hp[j] = f2bf(f[j] * inv);
  ((uint4*)p)[t] = v;
}

extern "C" void kernel_launch(void* const* d_in, const int* in_sizes, int n_in,
                              void* d_out, int out_size, void* d_ws, size_t ws_size,
                              hipStream_t stream) {
  const float* x  = (const float*)d_in[0];
  const float* y  = (const float*)d_in[1];
  const float* Wq = (const float*)d_in[2];
  const float* bq = (const float*)d_in[3];
  const float* Wk = (const float*)d_in[4];
  const float* bk = (const float*)d_in[5];
  const float* Wv = (const float*)d_in[6];
  const float* bv = (const float*)d_in[7];
  float* out = (float*)d_out;

  const int D = 1024;
  const long MB_ = 1l << 20;

  // ws layout (ushort units), aliases noted:
  ushort_t* ws  = (ushort_t*)d_ws;
  ushort_t* Wqt = ws;                    // [1024][1024] @0, 1M
  ushort_t* Wkv = ws + 1 * MB_;          // Wkt||Wvt = [2048][1024], 2M
  ushort_t* Wvt = ws + 2 * MB_;
  ushort_t* Qb  = ws + 3 * MB_;          // [8192][1024], 8M
  ushort_t* KV  = ws + 11 * MB_;         // [8192][2048] (K cols 0-1023, V 1024-2047), 16M
  ushort_t* yb  = ws + 27 * MB_;         // [8192][1024], 8M
  ushort_t* Vt  = ws + 27 * MB_;         // alias yb (yb dead after KV-gemm): [B][1024][2048]
  ushort_t* xb  = ws + 35 * MB_;         // [8192][1024], 8M
  ushort_t* Sb  = ws + 35 * MB_;         // alias xb (dead after Q-gemm): [B][2048][2048], 16M
  float*    bkv = (float*)(ws + 51 * MB_);  // [2048]

  dim3 blk(256);

  conv_f32_bf16<<<dim3(4096), blk, 0, stream>>>(x, xb);
  conv_f32_bf16<<<dim3(4096), blk, 0, stream>>>(y, yb);
  wtrans<<<dim3(32, 32), blk, 0, stream>>>(Wq, Wqt);
  wtrans<<<dim3(32, 32), blk, 0, stream>>>(Wk, Wkv);
  wtrans<<<dim3(32, 32), blk, 0, stream>>>(Wv, Wvt);
  bconcat<<<dim3(8), blk, 0, stream>>>(bk, bv, bkv);

  // Q = xb @ Wqt^T + bq -> [8192][1024]; grid 4x32 = 128
  gemm256<true, true><<<dim3(128), dim3(512), 0, stream>>>(
      xb, Wqt, Qb, bq, 4, 32, D, D, D, D, 0, 0, 0, 1.0f);
  // KV = yb @ Wkv^T + bkv -> [8192][2048]; grid 8x32 = 256 (1 block/CU)
  gemm256<true, true><<<dim3(256), dim3(512), 0, stream>>>(
      yb, Wkv, KV, bkv, 8, 32, D, D, D, 2048, 0, 0, 0, 1.0f);
  // Vt[b][d][t] = KV[b*2048+t][1024+d]
  transpose_bf16<<<dim3(16, 32, 4), blk, 0, stream>>>(
      KV + 1024, Vt, 2048, 2048, 2048l * 2048, 1024l * 2048);

  // S = (Q_b @ K_b^T)/32 -> bf16 [B][2048][2048]; grid 8x8x4 = 256
  gemm256<true, false><<<dim3(256), dim3(512), 0, stream>>>(
      Qb, KV, Sb, nullptr, 8, 8, D, D, 2048, 2048,
      2048l * 1024, 2048l * 2048, 2048l * 2048, 0.03125f);

  softmax_rows<<<dim3(8192), blk, 0, stream>>>(Sb);

  // out = P_b @ V_b (NT vs Vt [1024][2048]) -> fp32; 128^2 kernel, grid 512
  gemm_nt<false, false><<<dim3(512), blk, 0, stream>>>(
      Sb, Vt, out, nullptr, 8, 16, 2048, 2048, 2048, D,
      2048l * 2048, 1024l * 2048, 2048l * 1024, 1.0f);
}

// Round 4
// 189.836 us; speedup vs baseline: 2.6673x; 1.0718x over previous
//
#include <hip/hip_runtime.h>

typedef __bf16 bf16x8_t __attribute__((ext_vector_type(8)));
typedef float f32x4_t __attribute__((ext_vector_type(4)));
typedef unsigned short ushort_t;

__device__ __forceinline__ unsigned short f2bf(float f) {
  unsigned u = __float_as_uint(f);
  u = (u + 0x7FFFu + ((u >> 16) & 1u)) >> 16;
  return (unsigned short)u;
}
__device__ __forceinline__ float bf2f(unsigned short h) {
  return __uint_as_float(((unsigned)h) << 16);
}

// async global->LDS, 16B/lane. LDS dest = wave-uniform base + lane*16.
__device__ __forceinline__ void gload16(const void* g, void* l) {
  __builtin_amdgcn_global_load_lds(
      (const __attribute__((address_space(1))) unsigned int*)g,
      (__attribute__((address_space(3))) unsigned int*)l, 16, 0, 0);
}

#define BARRIER() __builtin_amdgcn_s_barrier()
#define LGKM0()                                        \
  do {                                                 \
    asm volatile("s_waitcnt lgkmcnt(0)" ::: "memory"); \
    __builtin_amdgcn_sched_barrier(0);                 \
  } while (0)

// ===========================================================================
// 256x256 8-phase NT GEMM (m201/m218 schedule). BK=64, 8 waves (2Mx4N).
// LDS 128KiB. Swizzle: LDS(row,chunk16B)=global(row,chunk^(row&7)), ds_read
// XORs the same. vmcnt(6) only at tile boundaries.
// ===========================================================================
template<bool OUT_BF16, bool HAS_BIAS>
__global__ __launch_bounds__(512, 2)
void gemm256(const ushort_t* __restrict__ A, const ushort_t* __restrict__ Bt,
             void* __restrict__ Cp, const float* __restrict__ bias,
             int gx, int gy, int K, int lda, int ldb, int ldc,
             long sA, long sB, long sC, float alpha)
{
  __shared__ __align__(16) ushort_t sm[2 * 32768];
  const int tid = threadIdx.x;
  const int lane = tid & 63;
  const int w = tid >> 6;
  const int wr = w >> 2, wc = w & 3;

  const int per = gridDim.x >> 3;
  int wg = blockIdx.x;
  wg = (wg & 7) * per + (wg >> 3);
  const int bz = wg / (gx * gy);
  const int rr = wg - bz * gx * gy;
  const int by = rr / gx, bx = rr - by * gx;
  const int bm = by * 256, bn = bx * 256;

  const int srr = lane >> 3;
  const int csw = ((lane & 7) ^ srr) << 3;
  const ushort_t* pA = A + (long)bz * sA + (long)(bm + w * 16 + srr) * lda + csw;
  const ushort_t* pB = Bt + (long)bz * sB + (long)(bn + w * 16 + srr) * ldb + csw;

  auto stA = [&](int buf, int h, int t) {
    const ushort_t* g = pA + (long)(h * 128) * lda + t * 64;
    ushort_t* d = sm + buf * 32768 + h * 8192 + w * 1024;
    gload16(g, d);
    gload16(g + 8 * lda, d + 512);
  };
  auto stB = [&](int buf, int h, int t) {
    const ushort_t* g = pB + (long)(h * 128) * ldb + t * 64;
    ushort_t* d = sm + buf * 32768 + 16384 + h * 8192 + w * 1024;
    gload16(g, d);
    gload16(g + 8 * ldb, d + 512);
  };

  const int q = lane >> 4, x7 = lane & 7;
  const int cx0 = ((0 + q) ^ x7) << 3;
  const int cx1 = ((4 + q) ^ x7) << 3;
  const int abase = wr * 8192 + (lane & 15) * 64;
  const int bbase = 16384 + wc * 4096 + (lane & 15) * 64;

  f32x4_t acc[8][4];
  const f32x4_t z4 = {0.f, 0.f, 0.f, 0.f};
#pragma unroll
  for (int m = 0; m < 8; ++m)
#pragma unroll
    for (int n = 0; n < 4; ++n) acc[m][n] = z4;

  bf16x8_t a[8], blo[4], bhi[4];

  stA(0, 0, 0); stA(0, 1, 0); stB(0, 0, 0); stB(0, 1, 0);
  stB(1, 0, 1); stB(1, 1, 1); stA(1, 0, 1);
  asm volatile("s_waitcnt vmcnt(6)" ::: "memory");
  __builtin_amdgcn_sched_barrier(0);
  BARRIER();

#define LDX(off) __builtin_bit_cast(bf16x8_t, *(const uint4*)(s + (off)))

  const int nt = K >> 6;
  for (int t = 0; t < nt; ++t) {
    const int buf = t & 1;
    const ushort_t* s = sm + buf * 32768;

    // P0: A0-3 + B-lo; MFMA [0-3][0-1]
#pragma unroll
    for (int mf = 0; mf < 4; ++mf) {
      a[mf * 2]     = LDX(abase + mf * 1024 + cx0);
      a[mf * 2 + 1] = LDX(abase + mf * 1024 + cx1);
    }
#pragma unroll
    for (int nf = 0; nf < 2; ++nf) {
      blo[nf * 2]     = LDX(bbase + nf * 1024 + cx0);
      blo[nf * 2 + 1] = LDX(bbase + nf * 1024 + cx1);
    }
    if (t + 1 < nt) stA(buf ^ 1, 1, t + 1);
    BARRIER();
    LGKM0();
    __builtin_amdgcn_s_setprio(1);
#pragma unroll
    for (int mf = 0; mf < 4; ++mf)
#pragma unroll
      for (int nf = 0; nf < 2; ++nf) {
        acc[mf][nf] = __builtin_amdgcn_mfma_f32_16x16x32_bf16(a[mf * 2], blo[nf * 2], acc[mf][nf], 0, 0, 0);
        acc[mf][nf] = __builtin_amdgcn_mfma_f32_16x16x32_bf16(a[mf * 2 + 1], blo[nf * 2 + 1], acc[mf][nf], 0, 0, 0);
      }
    __builtin_amdgcn_s_setprio(0);
    BARRIER();

    // P1: B-hi; MFMA [0-3][2-3]
#pragma unroll
    for (int nf = 0; nf < 2; ++nf) {
      bhi[nf * 2]     = LDX(bbase + (nf + 2) * 1024 + cx0);
      bhi[nf * 2 + 1] = LDX(bbase + (nf + 2) * 1024 + cx1);
    }
    if (t + 2 < nt) stB(buf, 0, t + 2);
    BARRIER();
    LGKM0();
    __builtin_amdgcn_s_setprio(1);
#pragma unroll
    for (int mf = 0; mf < 4; ++mf)
#pragma unroll
      for (int nf = 0; nf < 2; ++nf) {
        acc[mf][nf + 2] = __builtin_amdgcn_mfma_f32_16x16x32_bf16(a[mf * 2], bhi[nf * 2], acc[mf][nf + 2], 0, 0, 0);
        acc[mf][nf + 2] = __builtin_amdgcn_mfma_f32_16x16x32_bf16(a[mf * 2 + 1], bhi[nf * 2 + 1], acc[mf][nf + 2], 0, 0, 0);
      }
    __builtin_amdgcn_s_setprio(0);
    BARRIER();

    // P2: A4-7; MFMA [4-7][2-3]
#pragma unroll
    for (int mf = 0; mf < 4; ++mf) {
      a[mf * 2]     = LDX(abase + (mf + 4) * 1024 + cx0);
      a[mf * 2 + 1] = LDX(abase + (mf + 4) * 1024 + cx1);
    }
    if (t + 2 < nt) stB(buf, 1, t + 2);
    BARRIER();
    LGKM0();
    __builtin_amdgcn_s_setprio(1);
#pragma unroll
    for (int mf = 0; mf < 4; ++mf)
#pragma unroll
      for (int nf = 0; nf < 2; ++nf) {
        acc[mf + 4][nf + 2] = __builtin_amdgcn_mfma_f32_16x16x32_bf16(a[mf * 2], bhi[nf * 2], acc[mf + 4][nf + 2], 0, 0, 0);
        acc[mf + 4][nf + 2] = __builtin_amdgcn_mfma_f32_16x16x32_bf16(a[mf * 2 + 1], bhi[nf * 2 + 1], acc[mf + 4][nf + 2], 0, 0, 0);
      }
    __builtin_amdgcn_s_setprio(0);
    BARRIER();

    // P3: MFMA [4-7][0-1]; boundary vmcnt
    if (t + 2 < nt) stA(buf, 0, t + 2);
    __builtin_amdgcn_s_setprio(1);
#pragma unroll
    for (int mf = 0; mf < 4; ++mf)
#pragma unroll
      for (int nf = 0; nf < 2; ++nf) {
        acc[mf + 4][nf] = __builtin_amdgcn_mfma_f32_16x16x32_bf16(a[mf * 2], blo[nf * 2], acc[mf + 4][nf], 0, 0, 0);
        acc[mf + 4][nf] = __builtin_amdgcn_mfma_f32_16x16x32_bf16(a[mf * 2 + 1], blo[nf * 2 + 1], acc[mf + 4][nf], 0, 0, 0);
      }
    __builtin_amdgcn_s_setprio(0);
    if (t + 1 < nt) {
      if (t + 2 < nt) asm volatile("s_waitcnt vmcnt(6)" ::: "memory");
      else            asm volatile("s_waitcnt vmcnt(0)" ::: "memory");
      __builtin_amdgcn_sched_barrier(0);
    }
    BARRIER();
  }
#undef LDX

  const long zC = (long)bz * sC;
  const int r0 = q * 4;
  const int c0 = lane & 15;
#pragma unroll
  for (int mf = 0; mf < 8; ++mf) {
    const int grow0 = bm + wr * 128 + mf * 16 + r0;
#pragma unroll
    for (int nf = 0; nf < 4; ++nf) {
      const int gcol = bn + wc * 64 + nf * 16 + c0;
      float bv_ = 0.f;
      if constexpr (HAS_BIAS) bv_ = bias[gcol];
#pragma unroll
      for (int i = 0; i < 4; ++i) {
        const float v = acc[mf][nf][i] * alpha + bv_;
        if constexpr (OUT_BF16) {
          ((ushort_t*)Cp)[zC + (long)(grow0 + i) * ldc + gcol] = f2bf(v);
        } else {
          ((float*)Cp)[zC + (long)(grow0 + i) * ldc + gcol] = v;
        }
      }
    }
  }
}

// ===========================================================================
// 128x256 4-phase NT GEMM (full-fill variant for PV & Q). BK=64, 8 waves
// (2Mx4N, each 64x64). LDS 96KiB = 2buf x (A 16KB + B 32KB). Same swizzle.
// Staging: B(t+1) at P0 (other buf), A(t+2) at P3 (after A's last read P2);
// boundary vmcnt(2).
// ===========================================================================
template<bool OUT_BF16, bool HAS_BIAS>
__global__ __launch_bounds__(512, 2)
void gemm_hs(const ushort_t* __restrict__ A, const ushort_t* __restrict__ Bt,
             void* __restrict__ Cp, const float* __restrict__ bias,
             int gx, int gy, int K, int lda, int ldb, int ldc,
             long sA, long sB, long sC, float alpha)
{
  __shared__ __align__(16) ushort_t sm[2 * 24576];
  const int tid = threadIdx.x;
  const int lane = tid & 63;
  const int w = tid >> 6;
  const int wr = w >> 2, wc = w & 3;

  const int per = gridDim.x >> 3;
  int wg = blockIdx.x;
  wg = (wg & 7) * per + (wg >> 3);
  const int bz = wg / (gx * gy);
  const int rr = wg - bz * gx * gy;
  const int by = rr / gx, bx = rr - by * gx;
  const int bm = by * 128, bn = bx * 256;

  const int srr = lane >> 3;
  const int csw = ((lane & 7) ^ srr) << 3;
  const ushort_t* pA = A + (long)bz * sA + (long)(bm + w * 16 + srr) * lda + csw;
  const ushort_t* pB = Bt + (long)bz * sB + (long)(bn + w * 32 + srr) * ldb + csw;

  auto stA = [&](int buf, int t) {   // wave rows w*16..+15 (2 loads)
    const ushort_t* g = pA + t * 64;
    ushort_t* d = sm + buf * 24576 + w * 1024;
    gload16(g, d);
    gload16(g + 8 * lda, d + 512);
  };
  auto stB = [&](int buf, int t) {   // wave rows w*32..+31 (4 loads)
    const ushort_t* g = pB + t * 64;
    ushort_t* d = sm + buf * 24576 + 8192 + w * 2048;
    gload16(g, d);
    gload16(g + 8 * ldb, d + 512);
    gload16(g + 16 * ldb, d + 1024);
    gload16(g + 24 * ldb, d + 1536);
  };

  const int q = lane >> 4, x7 = lane & 7;
  const int cx0 = ((0 + q) ^ x7) << 3;
  const int cx1 = ((4 + q) ^ x7) << 3;
  const int abase = wr * 4096 + (lane & 15) * 64;
  const int bbase = 8192 + wc * 4096 + (lane & 15) * 64;

  f32x4_t acc[4][4];
  const f32x4_t z4 = {0.f, 0.f, 0.f, 0.f};
#pragma unroll
  for (int m = 0; m < 4; ++m)
#pragma unroll
    for (int n = 0; n < 4; ++n) acc[m][n] = z4;

  bf16x8_t a01[4], a23[4], blo[4], bhi[4];

  // prologue: tile0 (A+B), A(1); wait tile0 resident (leave A(1) in flight)
  stA(0, 0); stB(0, 0); stA(1, 1);
  asm volatile("s_waitcnt vmcnt(2)" ::: "memory");
  __builtin_amdgcn_sched_barrier(0);
  BARRIER();

#define LDX(off) __builtin_bit_cast(bf16x8_t, *(const uint4*)(s + (off)))

  const int nt = K >> 6;
  for (int t = 0; t < nt; ++t) {
    const int buf = t & 1;
    const ushort_t* s = sm + buf * 24576;

    // P0: A m0,m1 + B n0,n1; stage B(t+1) -> buf^1; MFMA [0-1][0-1]
    a01[0] = LDX(abase + cx0);        a01[1] = LDX(abase + cx1);
    a01[2] = LDX(abase + 1024 + cx0); a01[3] = LDX(abase + 1024 + cx1);
    blo[0] = LDX(bbase + cx0);        blo[1] = LDX(bbase + cx1);
    blo[2] = LDX(bbase + 1024 + cx0); blo[3] = LDX(bbase + 1024 + cx1);
    if (t + 1 < nt) stB(buf ^ 1, t + 1);
    BARRIER();
    LGKM0();
    __builtin_amdgcn_s_setprio(1);
#pragma unroll
    for (int mf = 0; mf < 2; ++mf)
#pragma unroll
      for (int nf = 0; nf < 2; ++nf) {
        acc[mf][nf] = __builtin_amdgcn_mfma_f32_16x16x32_bf16(a01[mf * 2], blo[nf * 2], acc[mf][nf], 0, 0, 0);
        acc[mf][nf] = __builtin_amdgcn_mfma_f32_16x16x32_bf16(a01[mf * 2 + 1], blo[nf * 2 + 1], acc[mf][nf], 0, 0, 0);
      }
    __builtin_amdgcn_s_setprio(0);
    BARRIER();

    // P1: B n2,n3; MFMA [0-1][2-3]
    bhi[0] = LDX(bbase + 2048 + cx0); bhi[1] = LDX(bbase + 2048 + cx1);
    bhi[2] = LDX(bbase + 3072 + cx0); bhi[3] = LDX(bbase + 3072 + cx1);
    BARRIER();
    LGKM0();
    __builtin_amdgcn_s_setprio(1);
#pragma unroll
    for (int mf = 0; mf < 2; ++mf)
#pragma unroll
      for (int nf = 0; nf < 2; ++nf) {
        acc[mf][nf + 2] = __builtin_amdgcn_mfma_f32_16x16x32_bf16(a01[mf * 2], bhi[nf * 2], acc[mf][nf + 2], 0, 0, 0);
        acc[mf][nf + 2] = __builtin_amdgcn_mfma_f32_16x16x32_bf16(a01[mf * 2 + 1], bhi[nf * 2 + 1], acc[mf][nf + 2], 0, 0, 0);
      }
    __builtin_amdgcn_s_setprio(0);
    BARRIER();

    // P2: A m2,m3; MFMA [2-3][2-3]
    a23[0] = LDX(abase + 2048 + cx0); a23[1] = LDX(abase + 2048 + cx1);
    a23[2] = LDX(abase + 3072 + cx0); a23[3] = LDX(abase + 3072 + cx1);
    BARRIER();
    LGKM0();
    __builtin_amdgcn_s_setprio(1);
#pragma unroll
    for (int mf = 0; mf < 2; ++mf)
#pragma unroll
      for (int nf = 0; nf < 2; ++nf) {
        acc[mf + 2][nf + 2] = __builtin_amdgcn_mfma_f32_16x16x32_bf16(a23[mf * 2], bhi[nf * 2], acc[mf + 2][nf + 2], 0, 0, 0);
        acc[mf + 2][nf + 2] = __builtin_amdgcn_mfma_f32_16x16x32_bf16(a23[mf * 2 + 1], bhi[nf * 2 + 1], acc[mf + 2][nf + 2], 0, 0, 0);
      }
    __builtin_amdgcn_s_setprio(0);
    BARRIER();

    // P3: stage A(t+2) -> buf (A last read in P2); MFMA [2-3][0-1]; boundary
    if (t + 2 < nt) stA(buf, t + 2);
    __builtin_amdgcn_s_setprio(1);
#pragma unroll
    for (int mf = 0; mf < 2; ++mf)
#pragma unroll
      for (int nf = 0; nf < 2; ++nf) {
        acc[mf + 2][nf] = __builtin_amdgcn_mfma_f32_16x16x32_bf16(a23[mf * 2], blo[nf * 2], acc[mf + 2][nf], 0, 0, 0);
        acc[mf + 2][nf] = __builtin_amdgcn_mfma_f32_16x16x32_bf16(a23[mf * 2 + 1], blo[nf * 2 + 1], acc[mf + 2][nf], 0, 0, 0);
      }
    __builtin_amdgcn_s_setprio(0);
    if (t + 1 < nt) {
      if (t + 2 < nt) asm volatile("s_waitcnt vmcnt(2)" ::: "memory");
      else            asm volatile("s_waitcnt vmcnt(0)" ::: "memory");
      __builtin_amdgcn_sched_barrier(0);
    }
    BARRIER();
  }
#undef LDX

  const long zC = (long)bz * sC;
  const int r0 = q * 4;
  const int c0 = lane & 15;
#pragma unroll
  for (int mf = 0; mf < 4; ++mf) {
    const int grow0 = bm + wr * 64 + mf * 16 + r0;
#pragma unroll
    for (int nf = 0; nf < 4; ++nf) {
      const int gcol = bn + wc * 64 + nf * 16 + c0;
      float bv_ = 0.f;
      if constexpr (HAS_BIAS) bv_ = bias[gcol];
#pragma unroll
      for (int i = 0; i < 4; ++i) {
        const float v = acc[mf][nf][i] * alpha + bv_;
        if constexpr (OUT_BF16) {
          ((ushort_t*)Cp)[zC + (long)(grow0 + i) * ldc + gcol] = f2bf(v);
        } else {
          ((float*)Cp)[zC + (long)(grow0 + i) * ldc + gcol] = v;
        }
      }
    }
  }
}

// fp32 -> bf16 bulk convert for x and y in one launch (8 elems/thread)
__global__ __launch_bounds__(256)
void conv2(const float* __restrict__ x, const float* __restrict__ y,
           ushort_t* __restrict__ xb, ushort_t* __restrict__ yb) {
  const int b = blockIdx.x;
  const float* in = (b < 4096) ? x : y;
  ushort_t* out = (b < 4096) ? xb : yb;
  const long i = (long)(b & 4095) * 256 + threadIdx.x;
  const float4 a = ((const float4*)in)[i * 2];
  const float4 c = ((const float4*)in)[i * 2 + 1];
  uint4 o;
  o.x = (unsigned)f2bf(a.x) | ((unsigned)f2bf(a.y) << 16);
  o.y = (unsigned)f2bf(a.z) | ((unsigned)f2bf(a.w) << 16);
  o.z = (unsigned)f2bf(c.x) | ((unsigned)f2bf(c.y) << 16);
  o.w = (unsigned)f2bf(c.z) | ((unsigned)f2bf(c.w) << 16);
  ((uint4*)out)[i] = o;
}

// Wt[n][k] = (bf16) W[k][n], D=1024, 3 weights in one launch (z selects)
__global__ __launch_bounds__(256)
void wtrans3(const float* __restrict__ W0, const float* __restrict__ W1,
             const float* __restrict__ W2, ushort_t* __restrict__ T0,
             ushort_t* __restrict__ T1, ushort_t* __restrict__ T2) {
  const float* W = (blockIdx.z == 0) ? W0 : (blockIdx.z == 1) ? W1 : W2;
  ushort_t* Wt = (blockIdx.z == 0) ? T0 : (blockIdx.z == 1) ? T1 : T2;
  __shared__ float tile[32][33];
  const int bx = blockIdx.x * 32;
  const int by = blockIdx.y * 32;
  const int t = threadIdx.x;
  const int c = t & 31, r0 = t >> 5;
#pragma unroll
  for (int i = 0; i < 4; ++i)
    tile[r0 + i * 8][c] = W[(long)(by + r0 + i * 8) * 1024 + bx + c];
  __syncthreads();
#pragma unroll
  for (int i = 0; i < 4; ++i)
    Wt[(long)(bx + r0 + i * 8) * 1024 + by + c] = f2bf(tile[c][r0 + i * 8]);
}

__global__ __launch_bounds__(256)
void bconcat(const float* __restrict__ a, const float* __restrict__ b,
             float* __restrict__ o) {
  const int i = blockIdx.x * 256 + threadIdx.x;
  o[i] = (i < 1024) ? a[i] : b[i - 1024];
}

// bf16 transpose with strides: out[c][r] = in[r][c], 64x64 tiles per batch
__global__ __launch_bounds__(256)
void transpose_bf16(const ushort_t* __restrict__ in, ushort_t* __restrict__ out,
                    int ld_in, int ld_out, long in_bs, long out_bs) {
  __shared__ ushort_t tt[64][65];
  in += (long)blockIdx.z * in_bs;
  out += (long)blockIdx.z * out_bs;
  const int r0 = blockIdx.y * 64, c0 = blockIdx.x * 64;
  const int tc = threadIdx.x & 31;
  const int tr = threadIdx.x >> 5;
#pragma unroll
  for (int i = 0; i < 8; ++i) {
    const unsigned v = *(const unsigned*)(in + (long)(r0 + tr + 8 * i) * ld_in + c0 + tc * 2);
    tt[tr + 8 * i][tc * 2] = (ushort_t)(v & 0xffff);
    tt[tr + 8 * i][tc * 2 + 1] = (ushort_t)(v >> 16);
  }
  __syncthreads();
#pragma unroll
  for (int i = 0; i < 8; ++i) {
    const unsigned v = (unsigned)tt[tc * 2][tr + 8 * i] |
                       ((unsigned)tt[tc * 2 + 1][tr + 8 * i] << 16);
    *(unsigned*)(out + (long)(c0 + tr + 8 * i) * ld_out + r0 + tc * 2) = v;
  }
}

// In-place softmax over rows of S (bf16), 2048 cols, one block per row.
__global__ __launch_bounds__(256)
void softmax_rows(ushort_t* __restrict__ S) {
  const long row = blockIdx.x;
  ushort_t* p = S + row * 2048;
  const int t = threadIdx.x;
  uint4 v = ((uint4*)p)[t];
  ushort_t* hp = (ushort_t*)&v;
  float f[8];
#pragma unroll
  for (int j = 0; j < 8; ++j) f[j] = bf2f(hp[j]);

  float m = f[0];
#pragma unroll
  for (int j = 1; j < 8; ++j) m = fmaxf(m, f[j]);
#pragma unroll
  for (int s = 32; s; s >>= 1) m = fmaxf(m, __shfl_xor(m, s, 64));
  __shared__ float redm[4];
  __shared__ float reds[4];
  const int wave = t >> 6, lane = t & 63;
  if (lane == 0) redm[wave] = m;
  __syncthreads();
  m = fmaxf(fmaxf(redm[0], redm[1]), fmaxf(redm[2], redm[3]));

  float sum = 0.f;
#pragma unroll
  for (int j = 0; j < 8; ++j) { f[j] = __expf(f[j] - m); sum += f[j]; }
#pragma unroll
  for (int s = 32; s; s >>= 1) sum += __shfl_xor(sum, s, 64);
  if (lane == 0) reds[wave] = sum;
  __syncthreads();
  sum = reds[0] + reds[1] + reds[2] + reds[3];
  const float inv = 1.0f / sum;
#pragma unroll
  for (int j = 0; j < 8; ++j) hp[j] = f2bf(f[j] * inv);
  ((uint4*)p)[t] = v;
}

extern "C" void kernel_launch(void* const* d_in, const int* in_sizes, int n_in,
                              void* d_out, int out_size, void* d_ws, size_t ws_size,
                              hipStream_t stream) {
  const float* x  = (const float*)d_in[0];
  const float* y  = (const float*)d_in[1];
  const float* Wq = (const float*)d_in[2];
  const float* bq = (const float*)d_in[3];
  const float* Wk = (const float*)d_in[4];
  const float* bk = (const float*)d_in[5];
  const float* Wv = (const float*)d_in[6];
  const float* bv = (const float*)d_in[7];
  float* out = (float*)d_out;

  const int D = 1024;
  const long MB_ = 1l << 20;

  ushort_t* ws  = (ushort_t*)d_ws;
  ushort_t* Wqt = ws;                    // [1024][1024], 1M
  ushort_t* Wkv = ws + 1 * MB_;          // Wkt||Wvt = [2048][1024], 2M
  ushort_t* Wvt = ws + 2 * MB_;
  ushort_t* Qb  = ws + 3 * MB_;          // [8192][1024], 8M
  ushort_t* KV  = ws + 11 * MB_;         // [8192][2048], 16M
  ushort_t* yb  = ws + 27 * MB_;         // [8192][1024], 8M
  ushort_t* Vt  = ws + 27 * MB_;         // alias yb: [B][1024][2048]
  ushort_t* xb  = ws + 35 * MB_;         // [8192][1024], 8M
  ushort_t* Sb  = ws + 35 * MB_;         // alias xb: [B][2048][2048], 16M
  float*    bkv = (float*)(ws + 51 * MB_);  // [2048]

  dim3 blk(256);

  conv2<<<dim3(8192), blk, 0, stream>>>(x, y, xb, yb);
  wtrans3<<<dim3(32, 32, 3), blk, 0, stream>>>(Wq, Wk, Wv, Wqt, Wkv, Wvt);
  bconcat<<<dim3(8), blk, 0, stream>>>(bk, bv, bkv);

  // Q = xb @ Wqt^T + bq -> [8192][1024]; 128x256 tiles: grid 4x64 = 256
  gemm_hs<true, true><<<dim3(256), dim3(512), 0, stream>>>(
      xb, Wqt, Qb, bq, 4, 64, D, D, D, D, 0, 0, 0, 1.0f);
  // KV = yb @ Wkv^T + bkv -> [8192][2048]; 256x256: grid 8x32 = 256
  gemm256<true, true><<<dim3(256), dim3(512), 0, stream>>>(
      yb, Wkv, KV, bkv, 8, 32, D, D, D, 2048, 0, 0, 0, 1.0f);
  // Vt[b][d][t] = KV[b*2048+t][1024+d]
  transpose_bf16<<<dim3(16, 32, 4), blk, 0, stream>>>(
      KV + 1024, Vt, 2048, 2048, 2048l * 2048, 1024l * 2048);

  // S = (Q_b @ K_b^T)/32 -> bf16 [B][2048][2048]; grid 8x8x4 = 256
  gemm256<true, false><<<dim3(256), dim3(512), 0, stream>>>(
      Qb, KV, Sb, nullptr, 8, 8, D, D, 2048, 2048,
      2048l * 1024, 2048l * 2048, 2048l * 2048, 0.03125f);

  softmax_rows<<<dim3(8192), blk, 0, stream>>>(Sb);

  // out = P_b @ V_b (NT vs Vt [1024][2048]) -> fp32; 128x256: grid 4x16x4=256
  gemm_hs<false, false><<<dim3(256), dim3(512), 0, stream>>>(
      Sb, Vt, out, nullptr, 4, 16, 2048, 2048, 2048, D,
      2048l * 2048, 1024l * 2048, 2048l * 1024, 1.0f);
}